// Round 3
// baseline (130.217 us; speedup 1.0000x reference)
//
#include <hip/hip_runtime.h>
#include <hip/hip_fp16.h>

// Triangulated-bilinear interp, B=8, N=262144 (512x512), T=2M targets.
// Round-8: interp is latency-bound on L2-hit rec loads (12 loads/wave in
// flight, ~200cy L2 hit, both pipes <10% busy). This round:
//  (a) 8 targets/thread -> 24 independent 16B rec loads issued before any
//      use (2x MLP/wave). VGPR ~180 -> 2 waves/SIMD = 8 waves/CU, which
//      matches the ~10 waves/CU actually resident before, so we trade
//      phantom occupancy for real per-wave parallelism.
//  (b) reciprocal-multiply instead of v_div chains for fx/fy (1-ulp index
//      shifts sit on cell/triangle boundaries where the interpolant is
//      continuous -> harmless vs 0.03125 tolerance).
// rec layout unchanged from Round-7: 16B per grid point (8 x fp16),
// N*16B = 4MiB = per-XCD L2 size; tgt/out stay nontemporal.

typedef float  f32x4 __attribute__((ext_vector_type(4)));
typedef unsigned int u32x4 __attribute__((ext_vector_type(4)));

__device__ __forceinline__ unsigned pack_h2(float lo, float hi) {
    union { __half2 h2; unsigned u; } cv;
    cv.h2 = __float22half2_rn(make_float2(lo, hi));
    return cv.u;
}

// Grid pack: rec[p] = 16B = 8 halves {b0..b7} of x[b][p].
// 4 points/thread: 8x dwordx4 coalesced loads, 4x dwordx4 contiguous stores.
__global__ __launch_bounds__(256) void build_grid16(
    const float* __restrict__ x,   // (B=8, N)
    u32x4* __restrict__ rec,       // (N) 16B per grid point
    int N)
{
    const int p0 = (blockIdx.x * blockDim.x + threadIdx.x) * 4;
    if (p0 + 4 <= N) {
        f32x4 v[8];
        #pragma unroll
        for (int b = 0; b < 8; ++b)
            v[b] = *reinterpret_cast<const f32x4*>(x + (long)b * N + p0);
        #pragma unroll
        for (int k = 0; k < 4; ++k) {
            u32x4 r;
            r[0] = pack_h2(v[0][k], v[1][k]);
            r[1] = pack_h2(v[2][k], v[3][k]);
            r[2] = pack_h2(v[4][k], v[5][k]);
            r[3] = pack_h2(v[6][k], v[7][k]);
            rec[p0 + k] = r;
        }
    } else {
        for (int p = p0; p < N; ++p) {
            u32x4 r;
            r[0] = pack_h2(x[p], x[(long)N + p]);
            r[1] = pack_h2(x[2L * N + p], x[3L * N + p]);
            r[2] = pack_h2(x[4L * N + p], x[5L * N + p]);
            r[3] = pack_h2(x[6L * N + p], x[7L * N + p]);
            rec[p] = r;
        }
    }
}

__device__ __forceinline__ void half8_to_float8(u32x4 u, float* f) {
    union { u32x4 v; __half2 h2[4]; } cv;
    cv.v = u;
    float2 a = __half22float2(cv.h2[0]); f[0] = a.x; f[1] = a.y;
    float2 b = __half22float2(cv.h2[1]); f[2] = b.x; f[3] = b.y;
    float2 c = __half22float2(cv.h2[2]); f[4] = c.x; f[5] = c.y;
    float2 d = __half22float2(cv.h2[3]); f[6] = d.x; f[7] = d.y;
}

#define TPT 8   // targets per thread

__global__ __launch_bounds__(256) void interp_rec_kernel(
    const u32x4* __restrict__ rec,   // (N) 16B per grid point, L2-resident
    const float* __restrict__ src_x,
    const float* __restrict__ src_y,
    const float* __restrict__ tgt_x,
    const float* __restrict__ tgt_y,
    const int* __restrict__ nx_p,
    float* __restrict__ out,
    int T, int N)
{
    const int nx = *nx_p;
    const int ny = N / nx;
    const float x0 = src_x[0];
    const float x1 = src_x[nx - 1];
    const float y0 = src_y[0];
    const float y1 = src_y[N - 1];
    // reciprocal-multiply: rdx = (nx-1)/(x1-x0) = 1/dx
    const float rdx = (float)(nx - 1) / (x1 - x0);
    const float rdy = (float)(ny - 1) / (y1 - y0);

    const int t0 = (blockIdx.x * blockDim.x + threadIdx.x) * TPT;
    if (t0 >= T) return;

    if (t0 + TPT <= T) {
        f32x4 txa = __builtin_nontemporal_load(
            reinterpret_cast<const f32x4*>(tgt_x + t0));
        f32x4 txb = __builtin_nontemporal_load(
            reinterpret_cast<const f32x4*>(tgt_x + t0 + 4));
        f32x4 tya = __builtin_nontemporal_load(
            reinterpret_cast<const f32x4*>(tgt_y + t0));
        f32x4 tyb = __builtin_nontemporal_load(
            reinterpret_cast<const f32x4*>(tgt_y + t0 + 4));

        // ---- Phase 1: all addresses + weights (no memory waits) ----
        int g0[TPT], g1[TPT], g2[TPT];
        float w0a[TPT], w1a[TPT], w2a[TPT];
        #pragma unroll
        for (int k = 0; k < TPT; ++k) {
            float tx = (k < 4) ? txa[k] : txb[k - 4];
            float ty = (k < 4) ? tya[k] : tyb[k - 4];
            float fx = (tx - x0) * rdx;
            float fy = (ty - y0) * rdy;
            float ix = fminf(fmaxf(floorf(fx), 0.0f), (float)(nx - 2));
            float iy = fminf(fmaxf(floorf(fy), 0.0f), (float)(ny - 2));
            float u = fx - ix;
            float v = fy - iy;
            bool lower = (u + v) <= 1.0f;
            int g = (int)iy * nx + (int)ix;
            g0[k] = g + (lower ? 0 : (nx + 1));  // p00 or p11
            g1[k] = g + 1;                       // p10
            g2[k] = g + nx;                      // p01
            w0a[k] = lower ? (1.0f - u - v) : (u + v - 1.0f);
            w1a[k] = lower ? u : (1.0f - v);
            w2a[k] = lower ? v : (1.0f - u);
        }

        // ---- Phase 2: issue ALL 24 loads before any use ----
        u32x4 r0[TPT], r1[TPT], r2[TPT];
        #pragma unroll
        for (int k = 0; k < TPT; ++k) { r0[k] = rec[g0[k]]; }
        #pragma unroll
        for (int k = 0; k < TPT; ++k) { r1[k] = rec[g1[k]]; }
        #pragma unroll
        for (int k = 0; k < TPT; ++k) { r2[k] = rec[g2[k]]; }

        // ---- Phase 3: convert + FMA ----
        float res[TPT][8];
        #pragma unroll
        for (int k = 0; k < TPT; ++k) {
            float f0[8], f1[8], f2[8];
            half8_to_float8(r0[k], f0);
            half8_to_float8(r1[k], f1);
            half8_to_float8(r2[k], f2);
            #pragma unroll
            for (int b = 0; b < 8; ++b)
                res[k][b] = f0[b] * w0a[k] + f1[b] * w1a[k] + f2[b] * w2a[k];
        }

        // ---- Phase 4: non-temporal coalesced stores (32B/batch/thread) ----
        #pragma unroll
        for (int b = 0; b < 8; ++b) {
            f32x4 ra = { res[0][b], res[1][b], res[2][b], res[3][b] };
            f32x4 rb = { res[4][b], res[5][b], res[6][b], res[7][b] };
            __builtin_nontemporal_store(
                ra, reinterpret_cast<f32x4*>(out + (long)b * T + t0));
            __builtin_nontemporal_store(
                rb, reinterpret_cast<f32x4*>(out + (long)b * T + t0 + 4));
        }
    } else {
        for (int t = t0; t < T; ++t) {
            float fx = (tgt_x[t] - x0) * rdx;
            float fy = (tgt_y[t] - y0) * rdy;
            float ix = fminf(fmaxf(floorf(fx), 0.0f), (float)(nx - 2));
            float iy = fminf(fmaxf(floorf(fy), 0.0f), (float)(ny - 2));
            float u = fx - ix;
            float v = fy - iy;
            bool lower = (u + v) <= 1.0f;
            int g = (int)iy * nx + (int)ix;
            u32x4 q0 = rec[g + (lower ? 0 : (nx + 1))];
            u32x4 q1 = rec[g + 1];
            u32x4 q2 = rec[g + nx];
            float w0 = lower ? (1.0f - u - v) : (u + v - 1.0f);
            float w1 = lower ? u : (1.0f - v);
            float w2 = lower ? v : (1.0f - u);
            float f0[8], f1[8], f2[8];
            half8_to_float8(q0, f0);
            half8_to_float8(q1, f1);
            half8_to_float8(q2, f2);
            for (int b = 0; b < 8; ++b)
                out[(long)b * T + t] = f0[b] * w0 + f1[b] * w1 + f2[b] * w2;
        }
    }
}

// Fallback: direct fp32 path, used only if ws too small / B != 8.
__global__ __launch_bounds__(256) void interp_fallback_kernel(
    const float* __restrict__ x,
    const float* __restrict__ src_x,
    const float* __restrict__ src_y,
    const float* __restrict__ tgt_x,
    const float* __restrict__ tgt_y,
    const int* __restrict__ nx_p,
    float* __restrict__ out,
    int T, int N, int B)
{
    const int nx = *nx_p;
    const int ny = N / nx;
    const float x0 = src_x[0];
    const float x1 = src_x[nx - 1];
    const float y0 = src_y[0];
    const float y1 = src_y[N - 1];
    const float rdx = (float)(nx - 1) / (x1 - x0);
    const float rdy = (float)(ny - 1) / (y1 - y0);

    const int t = blockIdx.x * blockDim.x + threadIdx.x;
    if (t >= T) return;
    float fx = (tgt_x[t] - x0) * rdx;
    float fy = (tgt_y[t] - y0) * rdy;
    float ix = fminf(fmaxf(floorf(fx), 0.0f), (float)(nx - 2));
    float iy = fminf(fmaxf(floorf(fy), 0.0f), (float)(ny - 2));
    float u = fx - ix;
    float v = fy - iy;
    int base = (int)iy * nx + (int)ix;
    bool lower = (u + v) <= 1.0f;
    int   i0 = lower ? base : (base + nx + 1);
    int   i1 = base + 1;
    int   i2 = base + nx;
    float w0 = lower ? (1.0f - u - v) : (u + v - 1.0f);
    float w1 = lower ? u : (1.0f - v);
    float w2 = lower ? v : (1.0f - u);
    for (int b = 0; b < B; ++b) {
        const float* xb = x + (long)b * N;
        out[(long)b * T + t] = xb[i0] * w0 + xb[i1] * w1 + xb[i2] * w2;
    }
}

extern "C" void kernel_launch(void* const* d_in, const int* in_sizes, int n_in,
                              void* d_out, int out_size, void* d_ws, size_t ws_size,
                              hipStream_t stream) {
    const float* x     = (const float*)d_in[0];
    const float* src_x = (const float*)d_in[1];
    const float* src_y = (const float*)d_in[2];
    const float* tgt_x = (const float*)d_in[3];
    const float* tgt_y = (const float*)d_in[4];
    const int*   nx_p  = (const int*)d_in[5];
    float* out = (float*)d_out;

    const int N = in_sizes[1];            // nx*ny = 262144
    const int T = in_sizes[3];            // 2,000,000
    const int B = in_sizes[0] / N;        // 8

    const size_t rec_bytes = (size_t)N * 16;   // 4 MiB at N=262144

    if (B == 8 && ws_size >= rec_bytes) {
        u32x4* rec = (u32x4*)d_ws;
        {
            const int block = 256;
            const int grid = ((N + 3) / 4 + block - 1) / block;
            build_grid16<<<grid, block, 0, stream>>>(x, rec, N);
        }
        {
            const int threads_needed = (T + TPT - 1) / TPT;
            const int block = 256;
            const int grid = (threads_needed + block - 1) / block;
            interp_rec_kernel<<<grid, block, 0, stream>>>(
                rec, src_x, src_y, tgt_x, tgt_y, nx_p, out, T, N);
        }
    } else {
        const int block = 256;
        const int grid = (T + block - 1) / block;
        interp_fallback_kernel<<<grid, block, 0, stream>>>(
            x, src_x, src_y, tgt_x, tgt_y, nx_p, out, T, N, B);
    }
}

// Round 4
// 129.348 us; speedup vs baseline: 1.0067x; 1.0067x over previous
//
#include <hip/hip_runtime.h>
#include <hip/hip_fp16.h>

// Triangulated-bilinear interp, B=8, N=262144 (512x512), T=2M targets.
// Round-9: persistent software-pipelined interp. Evidence: R3 cut HBM
// traffic 107->37MB with ZERO time change; both pipes <7% busy; in-flight
// lines/CU ~= 32 at ~200cy L2 latency -> MSHR/latency-bound with pipeline
// refill gaps (load -> drain -> compute -> store -> wave ends). Fix: grid
// = 512 blocks (2/CU, fully resident), grid-stride chunks of 4 targets,
// 3-deep rotation: consume chunk c while chunk c+1's 12 gathers are in
// flight and chunk c+2's tgt coords load. Disjoint A/B register stages so
// the compiler emits counted vmcnt (no full drains in steady state).
// rec layout unchanged (16B/point, 4MiB = per-XCD L2); builder unchanged.

typedef float  f32x4 __attribute__((ext_vector_type(4)));
typedef unsigned int u32x4 __attribute__((ext_vector_type(4)));

__device__ __forceinline__ unsigned pack_h2(float lo, float hi) {
    union { __half2 h2; unsigned u; } cv;
    cv.h2 = __float22half2_rn(make_float2(lo, hi));
    return cv.u;
}

// Grid pack: rec[p] = 16B = 8 halves {b0..b7} of x[b][p].
__global__ __launch_bounds__(256) void build_grid16(
    const float* __restrict__ x,   // (B=8, N)
    u32x4* __restrict__ rec,       // (N) 16B per grid point
    int N)
{
    const int p0 = (blockIdx.x * blockDim.x + threadIdx.x) * 4;
    if (p0 + 4 <= N) {
        f32x4 v[8];
        #pragma unroll
        for (int b = 0; b < 8; ++b)
            v[b] = *reinterpret_cast<const f32x4*>(x + (long)b * N + p0);
        #pragma unroll
        for (int k = 0; k < 4; ++k) {
            u32x4 r;
            r[0] = pack_h2(v[0][k], v[1][k]);
            r[1] = pack_h2(v[2][k], v[3][k]);
            r[2] = pack_h2(v[4][k], v[5][k]);
            r[3] = pack_h2(v[6][k], v[7][k]);
            rec[p0 + k] = r;
        }
    } else {
        for (int p = p0; p < N; ++p) {
            u32x4 r;
            r[0] = pack_h2(x[p], x[(long)N + p]);
            r[1] = pack_h2(x[2L * N + p], x[3L * N + p]);
            r[2] = pack_h2(x[4L * N + p], x[5L * N + p]);
            r[3] = pack_h2(x[6L * N + p], x[7L * N + p]);
            rec[p] = r;
        }
    }
}

__device__ __forceinline__ void half8_to_float8(u32x4 u, float* f) {
    union { u32x4 v; __half2 h2[4]; } cv;
    cv.v = u;
    float2 a = __half22float2(cv.h2[0]); f[0] = a.x; f[1] = a.y;
    float2 b = __half22float2(cv.h2[1]); f[2] = b.x; f[3] = b.y;
    float2 c = __half22float2(cv.h2[2]); f[4] = c.x; f[5] = c.y;
    float2 d = __half22float2(cv.h2[3]); f[6] = d.x; f[7] = d.y;
}

#define TPT 4   // targets per chunk

#define LOAD_TGT(c, tx, ty) do {                                          \
    const int _t0 = (c) * TPT;                                            \
    tx = __builtin_nontemporal_load(                                      \
        reinterpret_cast<const f32x4*>(tgt_x + _t0));                     \
    ty = __builtin_nontemporal_load(                                      \
        reinterpret_cast<const f32x4*>(tgt_y + _t0));                     \
} while (0)

#define GATHER(tx, ty, w0, w1, w2, r0, r1, r2) do {                       \
    _Pragma("unroll")                                                     \
    for (int k = 0; k < TPT; ++k) {                                       \
        float fx = (tx[k] - x0) * rdx;                                    \
        float fy = (ty[k] - y0) * rdy;                                    \
        float ix = fminf(fmaxf(floorf(fx), 0.0f), ixmax);                 \
        float iy = fminf(fmaxf(floorf(fy), 0.0f), iymax);                 \
        float u = fx - ix;                                                \
        float v = fy - iy;                                                \
        bool lower = (u + v) <= 1.0f;                                     \
        int g = (int)iy * nx + (int)ix;                                   \
        w0[k] = lower ? (1.0f - u - v) : (u + v - 1.0f);                  \
        w1[k] = lower ? u : (1.0f - v);                                   \
        w2[k] = lower ? v : (1.0f - u);                                   \
        r0[k] = rec[g + (lower ? 0 : (nx + 1))];                          \
        r1[k] = rec[g + 1];                                               \
        r2[k] = rec[g + nx];                                              \
    }                                                                     \
} while (0)

#define CONSUME(c, w0, w1, w2, r0, r1, r2) do {                           \
    const int _t0 = (c) * TPT;                                            \
    float res[TPT][8];                                                    \
    _Pragma("unroll")                                                     \
    for (int k = 0; k < TPT; ++k) {                                       \
        float f0[8], f1[8], f2[8];                                        \
        half8_to_float8(r0[k], f0);                                       \
        half8_to_float8(r1[k], f1);                                       \
        half8_to_float8(r2[k], f2);                                       \
        _Pragma("unroll")                                                 \
        for (int b = 0; b < 8; ++b)                                       \
            res[k][b] = f0[b] * w0[k] + f1[b] * w1[k] + f2[b] * w2[k];    \
    }                                                                     \
    _Pragma("unroll")                                                     \
    for (int b = 0; b < 8; ++b) {                                         \
        f32x4 r4 = { res[0][b], res[1][b], res[2][b], res[3][b] };        \
        __builtin_nontemporal_store(                                      \
            r4, reinterpret_cast<f32x4*>(out + (long)b * T + _t0));       \
    }                                                                     \
} while (0)

__global__ __launch_bounds__(256, 2) void interp_pipe_kernel(
    const u32x4* __restrict__ rec,   // (N) 16B per grid point, L2-resident
    const float* __restrict__ src_x,
    const float* __restrict__ src_y,
    const float* __restrict__ tgt_x,
    const float* __restrict__ tgt_y,
    const int* __restrict__ nx_p,
    float* __restrict__ out,
    int T, int N)
{
    const int nx = *nx_p;
    const int ny = N / nx;
    const float x0 = src_x[0];
    const float x1 = src_x[nx - 1];
    const float y0 = src_y[0];
    const float y1 = src_y[N - 1];
    const float rdx = (float)(nx - 1) / (x1 - x0);
    const float rdy = (float)(ny - 1) / (y1 - y0);
    const float ixmax = (float)(nx - 2);
    const float iymax = (float)(ny - 2);

    const int nch = T / TPT;                       // full chunks
    const int gsz = gridDim.x * blockDim.x;
    const int tid = blockIdx.x * blockDim.x + threadIdx.x;

    // Scalar tail for T % TPT leftovers (none at T=2M, kept for generality).
    {
        const int tail0 = nch * TPT;
        if (tid < T - tail0) {
            const int t = tail0 + tid;
            float fx = (tgt_x[t] - x0) * rdx;
            float fy = (tgt_y[t] - y0) * rdy;
            float ix = fminf(fmaxf(floorf(fx), 0.0f), ixmax);
            float iy = fminf(fmaxf(floorf(fy), 0.0f), iymax);
            float u = fx - ix;
            float v = fy - iy;
            bool lower = (u + v) <= 1.0f;
            int g = (int)iy * nx + (int)ix;
            u32x4 q0 = rec[g + (lower ? 0 : (nx + 1))];
            u32x4 q1 = rec[g + 1];
            u32x4 q2 = rec[g + nx];
            float w0 = lower ? (1.0f - u - v) : (u + v - 1.0f);
            float w1 = lower ? u : (1.0f - v);
            float w2 = lower ? v : (1.0f - u);
            float f0[8], f1[8], f2[8];
            half8_to_float8(q0, f0);
            half8_to_float8(q1, f1);
            half8_to_float8(q2, f2);
            for (int b = 0; b < 8; ++b)
                out[(long)b * T + t] = f0[b] * w0 + f1[b] * w1 + f2[b] * w2;
        }
    }

    int cCur = tid;
    if (cCur >= nch) return;
    int cNxt = cCur + gsz;
    int cPre = cNxt + gsz;

    // Two disjoint register stages (A/B); rotation by code duplication so
    // every array index is compile-time (rule: no runtime-indexed regs).
    f32x4 txA, tyA, txB, tyB;
    float wA0[TPT], wA1[TPT], wA2[TPT];
    float wB0[TPT], wB1[TPT], wB2[TPT];
    u32x4 rA0[TPT], rA1[TPT], rA2[TPT];
    u32x4 rB0[TPT], rB1[TPT], rB2[TPT];

    LOAD_TGT(cCur, txA, tyA);
    bool haveNxt = (cNxt < nch);
    if (haveNxt) LOAD_TGT(cNxt, txB, tyB);
    GATHER(txA, tyA, wA0, wA1, wA2, rA0, rA1, rA2);

    while (true) {
        // ---- CUR = A ----
        if (!haveNxt) { CONSUME(cCur, wA0, wA1, wA2, rA0, rA1, rA2); break; }
        if (cPre < nch) LOAD_TGT(cPre, txA, tyA);   // txA free (already consumed)
        GATHER(txB, tyB, wB0, wB1, wB2, rB0, rB1, rB2);
        CONSUME(cCur, wA0, wA1, wA2, rA0, rA1, rA2);
        cCur = cNxt; cNxt = cPre; cPre += gsz;
        haveNxt = (cNxt < nch);
        // ---- CUR = B ----
        if (!haveNxt) { CONSUME(cCur, wB0, wB1, wB2, rB0, rB1, rB2); break; }
        if (cPre < nch) LOAD_TGT(cPre, txB, tyB);
        GATHER(txA, tyA, wA0, wA1, wA2, rA0, rA1, rA2);
        CONSUME(cCur, wB0, wB1, wB2, rB0, rB1, rB2);
        cCur = cNxt; cNxt = cPre; cPre += gsz;
        haveNxt = (cNxt < nch);
    }
}

// Fallback: direct fp32 path, used only if ws too small / B != 8.
__global__ __launch_bounds__(256) void interp_fallback_kernel(
    const float* __restrict__ x,
    const float* __restrict__ src_x,
    const float* __restrict__ src_y,
    const float* __restrict__ tgt_x,
    const float* __restrict__ tgt_y,
    const int* __restrict__ nx_p,
    float* __restrict__ out,
    int T, int N, int B)
{
    const int nx = *nx_p;
    const int ny = N / nx;
    const float x0 = src_x[0];
    const float x1 = src_x[nx - 1];
    const float y0 = src_y[0];
    const float y1 = src_y[N - 1];
    const float rdx = (float)(nx - 1) / (x1 - x0);
    const float rdy = (float)(ny - 1) / (y1 - y0);

    const int t = blockIdx.x * blockDim.x + threadIdx.x;
    if (t >= T) return;
    float fx = (tgt_x[t] - x0) * rdx;
    float fy = (tgt_y[t] - y0) * rdy;
    float ix = fminf(fmaxf(floorf(fx), 0.0f), (float)(nx - 2));
    float iy = fminf(fmaxf(floorf(fy), 0.0f), (float)(ny - 2));
    float u = fx - ix;
    float v = fy - iy;
    int base = (int)iy * nx + (int)ix;
    bool lower = (u + v) <= 1.0f;
    int   i0 = lower ? base : (base + nx + 1);
    int   i1 = base + 1;
    int   i2 = base + nx;
    float w0 = lower ? (1.0f - u - v) : (u + v - 1.0f);
    float w1 = lower ? u : (1.0f - v);
    float w2 = lower ? v : (1.0f - u);
    for (int b = 0; b < B; ++b) {
        const float* xb = x + (long)b * N;
        out[(long)b * T + t] = xb[i0] * w0 + xb[i1] * w1 + xb[i2] * w2;
    }
}

extern "C" void kernel_launch(void* const* d_in, const int* in_sizes, int n_in,
                              void* d_out, int out_size, void* d_ws, size_t ws_size,
                              hipStream_t stream) {
    const float* x     = (const float*)d_in[0];
    const float* src_x = (const float*)d_in[1];
    const float* src_y = (const float*)d_in[2];
    const float* tgt_x = (const float*)d_in[3];
    const float* tgt_y = (const float*)d_in[4];
    const int*   nx_p  = (const int*)d_in[5];
    float* out = (float*)d_out;

    const int N = in_sizes[1];            // nx*ny = 262144
    const int T = in_sizes[3];            // 2,000,000
    const int B = in_sizes[0] / N;        // 8

    const size_t rec_bytes = (size_t)N * 16;   // 4 MiB at N=262144

    if (B == 8 && ws_size >= rec_bytes) {
        u32x4* rec = (u32x4*)d_ws;
        {
            const int block = 256;
            const int grid = ((N + 3) / 4 + block - 1) / block;
            build_grid16<<<grid, block, 0, stream>>>(x, rec, N);
        }
        {
            const int nch = T / TPT;
            int grid = (nch + 255) / 256;
            if (grid > 512) grid = 512;      // 2 blocks/CU, fully resident
            if (grid < 1) grid = 1;
            interp_pipe_kernel<<<grid, 256, 0, stream>>>(
                rec, src_x, src_y, tgt_x, tgt_y, nx_p, out, T, N);
        }
    } else {
        const int block = 256;
        const int grid = (T + block - 1) / block;
        interp_fallback_kernel<<<grid, block, 0, stream>>>(
            x, src_x, src_y, tgt_x, tgt_y, nx_p, out, T, N, B);
    }
}